// Round 3
// baseline (672.437 us; speedup 1.0000x reference)
//
#include <hip/hip_runtime.h>
#include <math.h>

#define NUM_EMB 1024
#define EMB_DIM 256
#define NROWS   65536
#define BM      64
#define BN      64
#define DK      32
#define NTHREADS 256

// out layout (float32, concatenated):
// [0, 16777216)        quantized_st
// [16777216, 16842752) encoding_indices (as float)
// [16842752]           vq_loss
// [16842753]           commitment_loss (= 0.25 * vq_loss numerically)
// [16842754]           perplexity
#define OFF_IDX  16777216
#define OFF_VQ   16842752

// ws layout:
// [0, 4096)      float c2[1024]  = ||e_k||^2, numpy-style sequential fp32
// [4096, 8192)   int   hist[1024]
// [8192, 8196)   float loss accumulator

// c2[k] = sequential fp32 sum over d of fl(e[d,k]^2)  (numpy axis-0 reduce order)
__global__ __launch_bounds__(NTHREADS) void vq_prep(
    const float* __restrict__ emb, float* __restrict__ cvec,
    int* __restrict__ hist, float* __restrict__ loss) {
  int k = blockIdx.x * blockDim.x + threadIdx.x;   // 4 blocks x 256 = 1024
  if (k < NUM_EMB) {
    float s = 0.f;
    for (int d = 0; d < EMB_DIM; ++d) {
      float v = emb[d * NUM_EMB + k];
      s = __fadd_rn(s, __fmul_rn(v, v));
    }
    cvec[k] = s;
    hist[k] = 0;
  }
  if (k == 0) *loss = 0.f;
}

// Emulates numpy float32: dist = fl( fl(r2[n] + c2[k]) - fl(2 * (z@e)[n,k]) )
// with r2 = numpy pairwise sum of squares, (z@e) = sequential-k fp32 FMA.
// Argmin = first occurrence of min (numpy rule).
__global__ __launch_bounds__(NTHREADS) void vq_main(
    const float* __restrict__ z, const float* __restrict__ emb,
    const float* __restrict__ cvec, float* __restrict__ out) {
  __shared__ float zc[BM][36];       // 64 rows x 32 d, stride 36
  __shared__ float ec[DK][68];       // 32 d x 64 codes, stride 68
  __shared__ float cT[NUM_EMB];      // ||e_k||^2
  __shared__ float r2s[BM];          // ||z_n||^2, numpy pairwise order
  __shared__ float pmm[BM][2][4];    // pairwise partials: row, half, m
  __shared__ float redv[BM][16];
  __shared__ int   redi[BM][16];

  const int tid = threadIdx.x;
  const int tx = tid & 15;           // code direction
  const int ty = tid >> 4;           // row direction
  const int n0 = blockIdx.x * BM;
  const float* zrow = z + (size_t)n0 * EMB_DIM;

  for (int i = tid; i < NUM_EMB; i += NTHREADS) cT[i] = cvec[i];

  // ---- pre-pass: r2[row] = numpy pairwise fp32 sum of z[row,:]**2 ----
  // numpy: n=256 -> pw(0:128)+pw(128:256); each 128: 8 accumulators r_j
  // (j = i mod 8, ascending i), combined ((r0+r1)+(r2+r3))+((r4+r5)+(r6+r7)).
  {
    const int prow = tid >> 2;       // 64 rows, 4 threads each
    const int pm = tid & 3;          // handles r_{2m}, r_{2m+1}
    float racc[2][2] = {{0.f, 0.f}, {0.f, 0.f}};   // [half][jj]
    for (int dc = 0; dc < EMB_DIM / DK; ++dc) {
      __syncthreads();
      #pragma unroll
      for (int it = 0; it < 2; ++it) {
        int i = tid + it * NTHREADS;
        int row = i >> 3, f4 = i & 7;
        float4 v = *(const float4*)(zrow + row * EMB_DIM + dc * DK + f4 * 4);
        *(float4*)(&zc[row][f4 * 4]) = v;
      }
      __syncthreads();
      const int half = dc >> 2;
      #pragma unroll
      for (int q = 0; q < 4; ++q) {
        #pragma unroll
        for (int jj = 0; jj < 2; ++jj) {
          float v = zc[prow][(pm * 2 + jj) + 8 * q];
          racc[half][jj] = __fadd_rn(racc[half][jj], __fmul_rn(v, v));
        }
      }
    }
    pmm[prow][0][pm] = __fadd_rn(racc[0][0], racc[0][1]);
    pmm[prow][1][pm] = __fadd_rn(racc[1][0], racc[1][1]);
    __syncthreads();
    if (tid < BM) {
      float h0 = __fadd_rn(__fadd_rn(pmm[tid][0][0], pmm[tid][0][1]),
                           __fadd_rn(pmm[tid][0][2], pmm[tid][0][3]));
      float h1 = __fadd_rn(__fadd_rn(pmm[tid][1][0], pmm[tid][1][1]),
                           __fadd_rn(pmm[tid][1][2], pmm[tid][1][3]));
      r2s[tid] = __fadd_rn(h0, h1);
    }
    __syncthreads();
  }

  float best[4];
  int   bidx[4];
  float myr2[4];
  #pragma unroll
  for (int r = 0; r < 4; ++r) {
    best[r] = 3.4e38f; bidx[r] = 0;
    myr2[r] = r2s[ty * 4 + r];
  }

  for (int j = 0; j < NUM_EMB / BN; ++j) {
    float acc[4][4] = {{0.f}};
    for (int dc = 0; dc < EMB_DIM / DK; ++dc) {
      const int dbase = dc * DK;
      __syncthreads();
      #pragma unroll
      for (int it = 0; it < 2; ++it) {
        int i = tid + it * NTHREADS;
        int row = i >> 3, f4 = i & 7;
        float4 v = *(const float4*)(zrow + row * EMB_DIM + dbase + f4 * 4);
        *(float4*)(&zc[row][f4 * 4]) = v;
      }
      #pragma unroll
      for (int it = 0; it < 2; ++it) {
        int i = tid + it * NTHREADS;
        int d = i >> 4, f4 = i & 15;
        float4 v = *(const float4*)(emb + (d + dbase) * NUM_EMB + j * BN + f4 * 4);
        *(float4*)(&ec[d][f4 * 4]) = v;
      }
      __syncthreads();
      // strict k-sequential fp32 FMA per (r,cc): matches BLAS sgemm microkernel
      #pragma unroll
      for (int d4 = 0; d4 < DK / 4; ++d4) {
        float4 A4[4], B4[4];
        #pragma unroll
        for (int r = 0; r < 4; ++r)
          A4[r] = *(const float4*)(&zc[ty * 4 + r][d4 * 4]);
        #pragma unroll
        for (int dd = 0; dd < 4; ++dd)
          B4[dd] = *(const float4*)(&ec[d4 * 4 + dd][tx * 4]);
        const float* Af = reinterpret_cast<const float*>(A4);
        const float* Bf = reinterpret_cast<const float*>(B4);
        #pragma unroll
        for (int dd = 0; dd < 4; ++dd)
          #pragma unroll
          for (int r = 0; r < 4; ++r)
            #pragma unroll
            for (int cc = 0; cc < 4; ++cc)
              acc[r][cc] = fmaf(Af[r * 4 + dd], Bf[dd * 4 + cc], acc[r][cc]);
      }
    }
    // fold: numpy-exact distance, first-index argmin (k ascending per thread)
    #pragma unroll
    for (int r = 0; r < 4; ++r) {
      #pragma unroll
      for (int cc = 0; cc < 4; ++cc) {
        int k = j * BN + tx * 4 + cc;
        float t1 = __fadd_rn(myr2[r], cT[k]);
        float t2 = __fmul_rn(2.0f, acc[r][cc]);
        float dist = __fsub_rn(t1, t2);
        if (dist < best[r]) { best[r] = dist; bidx[r] = k; }
      }
    }
  }

  __syncthreads();
  #pragma unroll
  for (int r = 0; r < 4; ++r) {
    redv[ty * 4 + r][tx] = best[r];
    redi[ty * 4 + r][tx] = bidx[r];
  }
  __syncthreads();
  if (tid < BM) {
    int row = tid;
    float v = redv[row][0];
    int   bi = redi[row][0];
    #pragma unroll
    for (int t = 1; t < 16; ++t) {
      float vv = redv[row][t];
      int   ii = redi[row][t];
      if (vv < v || (vv == v && ii < bi)) { v = vv; bi = ii; }
    }
    out[OFF_IDX + n0 + row] = (float)bi;
  }
}

// gather + straight-through write + loss partial + histogram
__global__ __launch_bounds__(NTHREADS) void vq_epi(
    const float* __restrict__ z, const float* __restrict__ emb,
    float* __restrict__ out, int* __restrict__ hist, float* __restrict__ loss) {
  __shared__ int ks[BM];
  __shared__ float wsum[4];
  const int tid = threadIdx.x;
  const int n0 = blockIdx.x * BM;
  const float* zrow = z + (size_t)n0 * EMB_DIM;
  if (tid < BM) {
    int k = (int)out[OFF_IDX + n0 + tid];
    ks[tid] = k;
    atomicAdd(&hist[k], 1);
  }
  __syncthreads();
  float sumsq = 0.f;
  #pragma unroll
  for (int it = 0; it < 16; ++it) {
    int g = tid + it * NTHREADS;          // float4 index in 64x256 tile
    int row = g >> 6;
    int d = (g & 63) * 4;
    int k = ks[row];
    float4 zv = *(const float4*)(zrow + row * EMB_DIM + d);
    float4 q;
    q.x = emb[(d + 0) * NUM_EMB + k];
    q.y = emb[(d + 1) * NUM_EMB + k];
    q.z = emb[(d + 2) * NUM_EMB + k];
    q.w = emb[(d + 3) * NUM_EMB + k];
    float4 df;
    df.x = q.x - zv.x; df.y = q.y - zv.y; df.z = q.z - zv.z; df.w = q.w - zv.w;
    sumsq = fmaf(df.x, df.x, sumsq);
    sumsq = fmaf(df.y, df.y, sumsq);
    sumsq = fmaf(df.z, df.z, sumsq);
    sumsq = fmaf(df.w, df.w, sumsq);
    *(float4*)(out + (size_t)(n0 + row) * EMB_DIM + d) = q;
  }
  #pragma unroll
  for (int off = 32; off > 0; off >>= 1) sumsq += __shfl_down(sumsq, off);
  if ((tid & 63) == 0) wsum[tid >> 6] = sumsq;
  __syncthreads();
  if (tid == 0) atomicAdd(loss, wsum[0] + wsum[1] + wsum[2] + wsum[3]);
}

__global__ __launch_bounds__(NTHREADS) void vq_finalize(
    const int* __restrict__ hist, const float* __restrict__ loss,
    float* __restrict__ out) {
  __shared__ float ws[4];
  int tid = threadIdx.x;
  float s = 0.f;
  for (int k = tid; k < NUM_EMB; k += NTHREADS) {
    float p = (float)hist[k] * (1.0f / 65536.0f);
    s += p * logf(p + 1e-10f);
  }
  #pragma unroll
  for (int off = 32; off > 0; off >>= 1) s += __shfl_down(s, off);
  if ((tid & 63) == 0) ws[tid >> 6] = s;
  __syncthreads();
  if (tid == 0) {
    float tot = ws[0] + ws[1] + ws[2] + ws[3];
    float vq = *loss * (1.0f / 16777216.0f);
    out[OFF_VQ + 0] = vq;
    out[OFF_VQ + 1] = 0.25f * vq;
    out[OFF_VQ + 2] = expf(-tot);
  }
}

extern "C" void kernel_launch(void* const* d_in, const int* in_sizes, int n_in,
                              void* d_out, int out_size, void* d_ws, size_t ws_size,
                              hipStream_t stream) {
  const float* z   = (const float*)d_in[0];     // 64*32*32*256
  const float* emb = (const float*)d_in[1];     // 256*1024
  float* out  = (float*)d_out;
  float* cvec = (float*)d_ws;
  int*   hist = (int*)((char*)d_ws + 4096);
  float* loss = (float*)((char*)d_ws + 8192);

  vq_prep<<<4, NTHREADS, 0, stream>>>(emb, cvec, hist, loss);
  vq_main<<<NROWS / BM, NTHREADS, 0, stream>>>(z, emb, cvec, out);
  vq_epi<<<NROWS / BM, NTHREADS, 0, stream>>>(z, emb, out, hist, loss);
  vq_finalize<<<1, NTHREADS, 0, stream>>>(hist, loss, out);
}

// Round 4
// 318.934 us; speedup vs baseline: 2.1084x; 2.1084x over previous
//
#include <hip/hip_runtime.h>
#include <math.h>

#define NUM_EMB 1024
#define EMB_DIM 256
#define NROWS   65536
#define NTHREADS 256
#define EPSF 1.5e-3f
#define GCAP 524288

// out layout (float32, concatenated):
#define OFF_IDX  16777216
#define OFF_VQ   16842752

// ws layout (bytes):
#define WS_C2    0         // float[1024]  ||e_k||^2 sequential fp32 (verified)
#define WS_HIST  4096      // int[1024]
#define WS_LOSS  8192      // float
#define WS_GCNT  8196      // int
#define WS_R2    8448      // float[65536] numpy-pairwise ||z_n||^2 (verified)
#define WS_SLOT  270592    // ull[65536]  packed (dist_bits<<32)|k
#define WS_ETF   794880    // float[1024][256]  emb^T fp32
#define WS_ETB   1843456   // ushort[1024][256] emb^T bf16
#define WS_GLIST 2367744   // uint[GCAP] packed (row<<10)|k

typedef __attribute__((ext_vector_type(8))) short bf16x8;
typedef __attribute__((ext_vector_type(4))) float f32x4;

__device__ __forceinline__ unsigned short f2bf(float x) {
  unsigned u = __float_as_uint(x);
  unsigned r = (u + 0x7FFFu + ((u >> 16) & 1u)) >> 16;
  return (unsigned short)r;
}

// c2[k] = sequential fp32 sum of fl(e[d,k]^2)  [verified round 3]
__global__ __launch_bounds__(NTHREADS) void vq_prep(
    const float* __restrict__ emb, float* __restrict__ cvec,
    int* __restrict__ hist, float* __restrict__ loss, int* __restrict__ gcnt) {
  int k = blockIdx.x * blockDim.x + threadIdx.x;
  if (k < NUM_EMB) {
    float s = 0.f;
    for (int d = 0; d < EMB_DIM; ++d) {
      float v = emb[d * NUM_EMB + k];
      s = __fadd_rn(s, __fmul_rn(v, v));
    }
    cvec[k] = s;
    hist[k] = 0;
  }
  if (k == 0) { *loss = 0.f; *gcnt = 0; }
}

// transpose emb [256][1024] -> embTf fp32 [1024][256] + embTbf bf16
__global__ __launch_bounds__(NTHREADS) void vq_tr(
    const float* __restrict__ emb, float* __restrict__ embTf,
    unsigned short* __restrict__ embTbf) {
  __shared__ float t[64][65];
  const int kt = blockIdx.x & 15, dt = blockIdx.x >> 4;
  const int tid = threadIdx.x;
  #pragma unroll
  for (int it = 0; it < 16; ++it) {
    int i = tid + it * NTHREADS, r = i >> 6, c = i & 63;
    t[r][c] = emb[(dt * 64 + r) * NUM_EMB + kt * 64 + c];
  }
  __syncthreads();
  #pragma unroll
  for (int it = 0; it < 16; ++it) {
    int i = tid + it * NTHREADS, r = i >> 6, c = i & 63;
    float v = t[c][r];
    embTf[(kt * 64 + r) * EMB_DIM + dt * 64 + c] = v;
    embTbf[(kt * 64 + r) * EMB_DIM + dt * 64 + c] = f2bf(v);
  }
}

// r2[n] = numpy pairwise fp32 sum of z[n,:]**2  [verified round 3, verbatim]
__global__ __launch_bounds__(NTHREADS) void vq_r2k(
    const float* __restrict__ z, float* __restrict__ r2out) {
  __shared__ float zc[64][36];
  __shared__ float pmm[64][2][4];
  const int tid = threadIdx.x;
  const int n0 = blockIdx.x * 64;
  const float* zrow = z + (size_t)n0 * EMB_DIM;
  const int prow = tid >> 2, pm = tid & 3;
  float racc[2][2] = {{0.f, 0.f}, {0.f, 0.f}};
  for (int dc = 0; dc < 8; ++dc) {
    __syncthreads();
    #pragma unroll
    for (int it = 0; it < 2; ++it) {
      int i = tid + it * NTHREADS, row = i >> 3, f4 = i & 7;
      *(float4*)(&zc[row][f4 * 4]) = *(const float4*)(zrow + row * EMB_DIM + dc * 32 + f4 * 4);
    }
    __syncthreads();
    const int half = dc >> 2;
    #pragma unroll
    for (int q = 0; q < 4; ++q)
      #pragma unroll
      for (int jj = 0; jj < 2; ++jj) {
        float v = zc[prow][(pm * 2 + jj) + 8 * q];
        racc[half][jj] = __fadd_rn(racc[half][jj], __fmul_rn(v, v));
      }
  }
  pmm[prow][0][pm] = __fadd_rn(racc[0][0], racc[0][1]);
  pmm[prow][1][pm] = __fadd_rn(racc[1][0], racc[1][1]);
  __syncthreads();
  if (tid < 64) {
    float h0 = __fadd_rn(__fadd_rn(pmm[tid][0][0], pmm[tid][0][1]),
                         __fadd_rn(pmm[tid][0][2], pmm[tid][0][3]));
    float h1 = __fadd_rn(__fadd_rn(pmm[tid][1][0], pmm[tid][1][1]),
                         __fadd_rn(pmm[tid][1][2], pmm[tid][1][3]));
    r2out[n0 + tid] = __fadd_rn(h0, h1);
  }
}

// bf16 MFMA approx-distance sweep + candidate capture.
// Block: 64 rows x all 1024 codes. 4 waves, each 64x64 per 256-col j-tile.
__global__ __launch_bounds__(NTHREADS, 2) void vq_mfma(
    const float* __restrict__ z, const unsigned short* __restrict__ embTbf,
    const float* __restrict__ cvec, unsigned long long* __restrict__ slots,
    int* __restrict__ gcnt, unsigned int* __restrict__ glist) {
  __shared__ unsigned short zc[64][264];   // A [m][k] bf16, stride 264 (16B-aligned rows, 2-way max)
  __shared__ unsigned short Bl[256][56];   // B^T [n][k] bf16 chunk (32 k), stride 56 (conflict-free)
  __shared__ float c2s[NUM_EMB];           // ||e||^2 + 1.0 shift (positivity for int-bit min)
  __shared__ int rowminb[64];              // running row-min, float bits (positive -> int monotone)
  __shared__ int lcnt, lbase, lcount;
  __shared__ unsigned int llist[512];

  const int tid = threadIdx.x;
  const int wave = tid >> 6, lane = tid & 63;
  const int quad = lane >> 4, l15 = lane & 15;
  const int n0 = blockIdx.x * 64;

  for (int i = tid; i < NUM_EMB; i += NTHREADS) c2s[i] = cvec[i] + 1.0f;
  if (tid < 64) {
    rowminb[tid] = 0x7F000000;             // large positive float bits
    slots[n0 + tid] = ~0ULL;
  }
  // stage A: z fp32 -> bf16 LDS, coalesced float4 reads
  #pragma unroll
  for (int it = 0; it < 16; ++it) {
    int g = tid + it * NTHREADS, row = g >> 6, f4 = g & 63;
    float4 v = *(const float4*)(z + (size_t)(n0 + row) * EMB_DIM + f4 * 4);
    ushort4 b;
    b.x = f2bf(v.x); b.y = f2bf(v.y); b.z = f2bf(v.z); b.w = f2bf(v.w);
    *(ushort4*)(&zc[row][f4 * 4]) = b;
  }

  for (int j = 0; j < 4; ++j) {            // 4 j-tiles x 256 codes
    f32x4 acc[4][4];                       // [rt][ct]
    #pragma unroll
    for (int rt = 0; rt < 4; ++rt)
      #pragma unroll
      for (int ct = 0; ct < 4; ++ct)
        acc[rt][ct] = (f32x4){0.f, 0.f, 0.f, 0.f};

    for (int kc = 0; kc < 8; ++kc) {
      __syncthreads();                     // Bl safe to overwrite (also covers A on first iter)
      #pragma unroll
      for (int it = 0; it < 4; ++it) {     // stage B chunk: 256 n x 32 k
        int nn = (tid >> 2) + it * 64, seg = tid & 3;
        uint4 v = *(const uint4*)(embTbf + (size_t)(j * 256 + nn) * EMB_DIM + kc * 32 + seg * 8);
        *(uint4*)(&Bl[nn][seg * 8]) = v;
      }
      __syncthreads();
      bf16x8 av[4], bv[4];
      #pragma unroll
      for (int rt = 0; rt < 4; ++rt)
        av[rt] = *(const bf16x8*)(&zc[rt * 16 + l15][kc * 32 + quad * 8]);
      #pragma unroll
      for (int ct = 0; ct < 4; ++ct)
        bv[ct] = *(const bf16x8*)(&Bl[wave * 64 + ct * 16 + l15][quad * 8]);
      #pragma unroll
      for (int rt = 0; rt < 4; ++rt)
        #pragma unroll
        for (int ct = 0; ct < 4; ++ct)
          acc[rt][ct] = __builtin_amdgcn_mfma_f32_16x16x32_bf16(av[rt], bv[ct], acc[rt][ct], 0, 0, 0);
    }

    // tile row-min: dist' = 1 + c2 - 2s  (C/D: col=lane&15, row=quad*4+reg)
    #pragma unroll
    for (int rt = 0; rt < 4; ++rt)
      #pragma unroll
      for (int reg = 0; reg < 4; ++reg) {
        float m = 1e30f;
        #pragma unroll
        for (int ct = 0; ct < 4; ++ct) {
          int k = j * 256 + wave * 64 + ct * 16 + l15;
          float d = fmaf(-2.f, acc[rt][ct][reg], c2s[k]);
          m = fminf(m, d);
        }
        #pragma unroll
        for (int off = 1; off < 16; off <<= 1)
          m = fminf(m, __shfl_xor(m, off));
        if (l15 == 0)
          atomicMin(&rowminb[rt * 16 + quad * 4 + reg], __float_as_int(m));
      }
    if (tid == 0) lcnt = 0;
    __syncthreads();                        // row mins final; lcnt ready

    // capture candidates within EPSF of running min
    #pragma unroll
    for (int rt = 0; rt < 4; ++rt)
      #pragma unroll
      for (int reg = 0; reg < 4; ++reg) {
        int rowl = rt * 16 + quad * 4 + reg;
        float fmin = __int_as_float(rowminb[rowl]);
        #pragma unroll
        for (int ct = 0; ct < 4; ++ct) {
          int k = j * 256 + wave * 64 + ct * 16 + l15;
          float d = fmaf(-2.f, acc[rt][ct][reg], c2s[k]);
          if (d <= fmin + EPSF) {
            int id = atomicAdd(&lcnt, 1);
            if (id < 512) llist[id] = ((unsigned)(n0 + rowl) << 10) | (unsigned)k;
          }
        }
      }
    __syncthreads();
    if (tid == 0) {
      int c = lcnt < 512 ? lcnt : 512;
      lcount = c;
      lbase = atomicAdd(gcnt, c);
    }
    __syncthreads();
    for (int i = tid; i < lcount; i += NTHREADS)
      if (lbase + i < GCAP) glist[lbase + i] = llist[i];
    __syncthreads();                        // llist/lcnt reuse next j
  }
}

// exact numpy-fp32 re-evaluation of captured pairs [arithmetic verified round 3]
__global__ __launch_bounds__(NTHREADS) void vq_refine(
    const float* __restrict__ z, const float* __restrict__ embTf,
    const float* __restrict__ r2, const float* __restrict__ cvec,
    const int* __restrict__ gcnt, const unsigned int* __restrict__ glist,
    unsigned long long* __restrict__ slots) {
  int n = *gcnt; if (n > GCAP) n = GCAP;
  for (int i = blockIdx.x * NTHREADS + threadIdx.x; i < n;
       i += gridDim.x * NTHREADS) {
    unsigned e = glist[i];
    int grow = (int)(e >> 10), k = (int)(e & 1023);
    const float* zr = z + (size_t)grow * EMB_DIM;
    const float* er = embTf + (size_t)k * EMB_DIM;
    float s = 0.f;
    for (int d = 0; d < EMB_DIM; ++d)       // strict sequential-d fmaf chain
      s = fmaf(zr[d], er[d], s);
    float dist = __fsub_rn(__fadd_rn(r2[grow], cvec[k]), __fmul_rn(2.0f, s));
    unsigned long long key =
        ((unsigned long long)__float_as_uint(dist) << 32) | (unsigned)k;
    atomicMin(&slots[grow], key);
  }
}

// final index + gather + straight-through write + loss + histogram
__global__ __launch_bounds__(NTHREADS) void vq_epi(
    const float* __restrict__ z, const float* __restrict__ embTf,
    const unsigned long long* __restrict__ slots,
    float* __restrict__ out, int* __restrict__ hist, float* __restrict__ loss) {
  __shared__ int ks[64];
  __shared__ float wsum[4];
  const int tid = threadIdx.x;
  const int n0 = blockIdx.x * 64;
  const float* zrow = z + (size_t)n0 * EMB_DIM;
  if (tid < 64) {
    int k = (int)(slots[n0 + tid] & 1023ULL);
    ks[tid] = k;
    out[OFF_IDX + n0 + tid] = (float)k;
    atomicAdd(&hist[k], 1);
  }
  __syncthreads();
  float sumsq = 0.f;
  #pragma unroll
  for (int it = 0; it < 16; ++it) {
    int g = tid + it * NTHREADS;
    int row = g >> 6;
    int d = (g & 63) * 4;
    int k = ks[row];
    float4 zv = *(const float4*)(zrow + row * EMB_DIM + d);
    float4 q = *(const float4*)(embTf + (size_t)k * EMB_DIM + d);
    float4 df;
    df.x = q.x - zv.x; df.y = q.y - zv.y; df.z = q.z - zv.z; df.w = q.w - zv.w;
    sumsq = fmaf(df.x, df.x, sumsq);
    sumsq = fmaf(df.y, df.y, sumsq);
    sumsq = fmaf(df.z, df.z, sumsq);
    sumsq = fmaf(df.w, df.w, sumsq);
    *(float4*)(out + (size_t)(n0 + row) * EMB_DIM + d) = q;
  }
  #pragma unroll
  for (int off = 32; off > 0; off >>= 1) sumsq += __shfl_down(sumsq, off);
  if ((tid & 63) == 0) wsum[tid >> 6] = sumsq;
  __syncthreads();
  if (tid == 0) atomicAdd(loss, wsum[0] + wsum[1] + wsum[2] + wsum[3]);
}

__global__ __launch_bounds__(NTHREADS) void vq_finalize(
    const int* __restrict__ hist, const float* __restrict__ loss,
    float* __restrict__ out) {
  __shared__ float ws[4];
  int tid = threadIdx.x;
  float s = 0.f;
  for (int k = tid; k < NUM_EMB; k += NTHREADS) {
    float p = (float)hist[k] * (1.0f / 65536.0f);
    s += p * logf(p + 1e-10f);
  }
  #pragma unroll
  for (int off = 32; off > 0; off >>= 1) s += __shfl_down(s, off);
  if ((tid & 63) == 0) ws[tid >> 6] = s;
  __syncthreads();
  if (tid == 0) {
    float tot = ws[0] + ws[1] + ws[2] + ws[3];
    float vq = *loss * (1.0f / 16777216.0f);
    out[OFF_VQ + 0] = vq;
    out[OFF_VQ + 1] = 0.25f * vq;
    out[OFF_VQ + 2] = expf(-tot);
  }
}

extern "C" void kernel_launch(void* const* d_in, const int* in_sizes, int n_in,
                              void* d_out, int out_size, void* d_ws, size_t ws_size,
                              hipStream_t stream) {
  const float* z   = (const float*)d_in[0];
  const float* emb = (const float*)d_in[1];
  float* out = (float*)d_out;
  char* ws = (char*)d_ws;
  float* cvec   = (float*)(ws + WS_C2);
  int*   hist   = (int*)(ws + WS_HIST);
  float* loss   = (float*)(ws + WS_LOSS);
  int*   gcnt   = (int*)(ws + WS_GCNT);
  float* r2     = (float*)(ws + WS_R2);
  unsigned long long* slots = (unsigned long long*)(ws + WS_SLOT);
  float* embTf  = (float*)(ws + WS_ETF);
  unsigned short* embTbf = (unsigned short*)(ws + WS_ETB);
  unsigned int* glist = (unsigned int*)(ws + WS_GLIST);

  vq_prep<<<4, NTHREADS, 0, stream>>>(emb, cvec, hist, loss, gcnt);
  vq_tr<<<64, NTHREADS, 0, stream>>>(emb, embTf, embTbf);
  vq_r2k<<<NROWS / 64, NTHREADS, 0, stream>>>(z, r2);
  vq_mfma<<<NROWS / 64, NTHREADS, 0, stream>>>(z, embTbf, cvec, slots, gcnt, glist);
  vq_refine<<<512, NTHREADS, 0, stream>>>(z, embTf, r2, cvec, gcnt, glist, slots);
  vq_epi<<<NROWS / 64, NTHREADS, 0, stream>>>(z, embTf, slots, out, hist, loss);
  vq_finalize<<<1, NTHREADS, 0, stream>>>(hist, loss, out);
}